// Round 3
// baseline (357.615 us; speedup 1.0000x reference)
//
#include <hip/hip_runtime.h>

// FeatLUT: out[f] = quantize( mean_p( msb[idx_m(p)][f] + lsb[idx_l(p)][f] ) )
// idx = 16*(289*c0 + 17*c1 + c2)  -> only 17^3 = 4913 distinct rows used.
//
// R4 post-mortems:
//  - R2 (268us): __launch_bounds__(512,8) squeezed VGPR 52->28, serialized the
//    load bundles (VALUBusy 6%). NEVER set min-waves here; plain (256) gives 52.
//  - R3 (303us): 2048 blocks x 20 atomicAdds to ONE cacheline = 40960
//    serialized global atomics (~160us tail) -- the exact mine the original
//    session documented. Partials must be DISTINCT-ADDRESS non-contended.
// Keep the two clean wins: packed 19.7KB hist (8 blocks/CU by LDS) and
// interleaved 48B cc rows. Grid 2048 (-> 32 waves/CU, 2x R1 in-flight bytes)
// when ws_size permits the 160KB partial array; else 1024 (R1-equivalent).

#define NBINS 4913            // 17^3
#define NPIX  (2048 * 2048)   // 4194304 = 2^22
#define G4    (NPIX / 4)      // 1048576 float4 groups per channel plane
#define NFEAT 20
#define MT    256

// ws layout (fixed offsets, grid-size independent):
//   cc      @ 0      : 4913 * 12 dwords = 235824 B (48B rows: m0..m4 l0..l4 p p)
//   counter @ 235824 : 1 uint
//   partial @ 235840 : gridDim.x * 20 ints (2048 blocks -> 163840 B)
#define CTR_OFF  235824
#define PART_OFF 235840

// ---------------------------------------------------------------------------
// Kernel 0: compact used LUT rows (row 16j, j in [0,4913)) into interleaved
// 48-byte rows; zeroes the completion counter (ws is poisoned each iter).
// Handles both harness layouts (raw int8 bytes vs widened int32): random
// packed bytes essentially never stay in [-32,32) 64x in a row.
// ---------------------------------------------------------------------------
__global__ __launch_bounds__(256) void compact_k(const int* __restrict__ msb,
                                                 const int* __restrict__ lsb,
                                                 int* __restrict__ cc,
                                                 unsigned* __restrict__ counter) {
    if (blockIdx.x == 0 && threadIdx.x == 0) *counter = 0u;

    int ok = 1;
    for (int i = 0; i < 64; ++i) {
        int v = msb[i];
        ok &= (v >= -32 && v < 32);
    }
    const bool is_int32 = (ok != 0);

    const int total = NBINS * 10;                 // 49130 source dwords
    int t = blockIdx.x * 256 + threadIdx.x;       // grid 192*256 = 49152 >= total
    if (t >= total) return;
    int j = t / 10;
    int k = t - j * 10;                           // 0-4: msb dword, 5-9: lsb dword
    const int* base = (k < 5) ? msb : lsb;
    int kk = (k < 5) ? k : k - 5;
    int w;
    if (is_int32) {
        // int per element; row 16j starts at element 16j*20 = 320j
        const int* r = base + j * 320 + kk * 4;
        w = (int)((unsigned)(r[0] & 0xff) | ((unsigned)(r[1] & 0xff) << 8) |
                  ((unsigned)(r[2] & 0xff) << 16) | ((unsigned)(r[3] & 0xff) << 24));
    } else {
        // raw int8; row 16j at byte 320j -> dword 80j, 5 dwords/row
        w = base[j * 80 + kk];
    }
    cc[j * 12 + k] = w;                           // pads (10,11) never read
}

// sign-extend byte lane of packed dword
#define SX(w, sh) ((int)((unsigned)(w) << (sh)) >> 24)
// h <= 4096, |byte| <= 128: product < 2^20, fits v_mad_i32_i24 (full-rate)
#define MACW(h, w, base)                                \
    acc[(base) + 0] += __mul24((h), SX((w), 24));       \
    acc[(base) + 1] += __mul24((h), SX((w), 16));       \
    acc[(base) + 2] += __mul24((h), SX((w), 8));        \
    acc[(base) + 3] += __mul24((h), ((int)(w) >> 24));

#define IDX4(d, v0, v1, v2)                                      \
    int d##0 = (int)fmaf(v0.x, 289.0f, fmaf(v1.x, 17.0f, v2.x)); \
    int d##1 = (int)fmaf(v0.y, 289.0f, fmaf(v1.y, 17.0f, v2.y)); \
    int d##2 = (int)fmaf(v0.z, 289.0f, fmaf(v1.z, 17.0f, v2.z)); \
    int d##3 = (int)fmaf(v0.w, 289.0f, fmaf(v1.w, 17.0f, v2.w));

__device__ __forceinline__ int wave_red(int v) {
#pragma unroll
    for (int o = 32; o > 0; o >>= 1) v += __shfl_xor(v, o, 64);
    return v;
}

// ---------------------------------------------------------------------------
// Kernel 1: main. gridDim.x x 256. Packed hist (msb lo16, lsb hi16; per-block
// count per table <= 4096 < 2^16). R1's proven grid-stride phase-A loop.
// Per-block NON-CONTENDED partial row (distinct addresses), last block sums.
// ---------------------------------------------------------------------------
__global__ __launch_bounds__(MT) void feat_main(const float* __restrict__ xin,
                                                const float* __restrict__ xs,
                                                const int* __restrict__ cc,
                                                int* __restrict__ partial,
                                                unsigned* __restrict__ counter,
                                                float* __restrict__ out) {
    __shared__ int hist[NBINS];                 // 19652 B -> 8 blocks/CU
    __shared__ int wsum[MT / 64][NFEAT];
    __shared__ unsigned last_s;

    for (int i = threadIdx.x; i < NBINS; i += MT) hist[i] = 0;
    __syncthreads();

    const float4* a = (const float4*)xin;
    const float4* b = (const float4*)xs;
    const int nt = gridDim.x * MT;              // exact divisor of G4
    for (int g = blockIdx.x * MT + threadIdx.x; g < G4; g += nt) {
        float4 a0 = a[g], a1 = a[g + G4], a2 = a[g + 2 * G4];
        float4 b0 = b[g], b1 = b[g + G4], b2 = b[g + 2 * G4];

        IDX4(m, a0, a1, a2)
        IDX4(s, b0, b1, b2)

        atomicAdd(&hist[m0], 1);
        atomicAdd(&hist[m1], 1);
        atomicAdd(&hist[m2], 1);
        atomicAdd(&hist[m3], 1);
        atomicAdd(&hist[s0], 1 << 16);
        atomicAdd(&hist[s1], 1 << 16);
        atomicAdd(&hist[s2], 1 << 16);
        atomicAdd(&hist[s3], 1 << 16);
    }
    __syncthreads();

    // per-block dot: acc[f] += hm[j]*msb_row[j][f] + hl[j]*lsb_row[j][f]
    int acc[NFEAT];
#pragma unroll
    for (int f = 0; f < NFEAT; ++f) acc[f] = 0;

    for (int j = threadIdx.x; j < NBINS; j += MT) {   // 19-20 iters
        int h = hist[j];
        if (h == 0) continue;                          // 19-43% empty
        int hm = h & 0xffff;
        int hl = (int)((unsigned)h >> 16);
        const int4* r = (const int4*)(cc + j * 12);    // 48B row, 16B-aligned
        int4 q0 = r[0], q1 = r[1], q2 = r[2];
        MACW(hm, q0.x, 0)  MACW(hm, q0.y, 4)  MACW(hm, q0.z, 8)
        MACW(hm, q0.w, 12) MACW(hm, q1.x, 16)
        MACW(hl, q1.y, 0)  MACW(hl, q1.z, 4)  MACW(hl, q1.w, 8)
        MACW(hl, q2.x, 12) MACW(hl, q2.y, 16)
    }

    // wave butterfly -> per-wave LDS row -> thread f sums 4 waves ->
    // one distinct-address partial row per block (NO contended atomics).
    const int lane = threadIdx.x & 63;
    const int wv = threadIdx.x >> 6;
#pragma unroll
    for (int f = 0; f < NFEAT; ++f) {
        int v = wave_red(acc[f]);
        if (lane == 0) wsum[wv][f] = v;
    }
    __syncthreads();
    if (threadIdx.x < NFEAT) {
        int s = 0;
#pragma unroll
        for (int w = 0; w < MT / 64; ++w) s += wsum[w][threadIdx.x];
        __hip_atomic_store(&partial[blockIdx.x * NFEAT + threadIdx.x], s,
                           __ATOMIC_RELAXED, __HIP_MEMORY_SCOPE_AGENT);
    }

    // last-block finalize: release fence + one counter atomic per block
    // (staggered, single address, ~gridDim.x total -> negligible).
    __threadfence();
    __syncthreads();
    if (threadIdx.x == 0)
        last_s = __hip_atomic_fetch_add(counter, 1u, __ATOMIC_ACQ_REL,
                                        __HIP_MEMORY_SCOPE_AGENT);
    __syncthreads();
    if (last_s != gridDim.x - 1) return;

    __threadfence();  // acquire: see all blocks' partial rows
    int accf[NFEAT];
#pragma unroll
    for (int f = 0; f < NFEAT; ++f) accf[f] = 0;
    for (int r = threadIdx.x; r < (int)gridDim.x; r += MT) {
        const int* p = partial + r * NFEAT;
#pragma unroll
        for (int f = 0; f < NFEAT; ++f)
            accf[f] += __hip_atomic_load(&p[f], __ATOMIC_RELAXED,
                                         __HIP_MEMORY_SCOPE_AGENT);
    }
#pragma unroll
    for (int f = 0; f < NFEAT; ++f) {
        int v = wave_red(accf[f]);
        if (lane == 0) wsum[wv][f] = v;
    }
    __syncthreads();
    if (threadIdx.x < NFEAT) {
        int s = 0;
#pragma unroll
        for (int w = 0; w < MT / 64; ++w) s += wsum[w][threadIdx.x];
        // mean*4 = S / 2^20 exactly; RNE rint == jnp.round
        double m4 = (double)s * (1.0 / 1048576.0);
        double r = rint(m4);
        float v = (float)(r * 0.25);
        v = fminf(fmaxf(v, -32.0f), 31.75f);
        out[threadIdx.x] = v;
    }
}

extern "C" void kernel_launch(void* const* d_in, const int* in_sizes, int n_in,
                              void* d_out, int out_size, void* d_ws, size_t ws_size,
                              hipStream_t stream) {
    const float* xin = (const float*)d_in[0];
    const float* xs = (const float*)d_in[1];
    const int* msb = (const int*)d_in[2];
    const int* lsb = (const int*)d_in[3];
    float* out = (float*)d_out;

    int* cc = (int*)d_ws;
    unsigned* counter = (unsigned*)((char*)d_ws + CTR_OFF);
    int* partial = (int*)((char*)d_ws + PART_OFF);

    // 2048 blocks -> 8 blocks/CU (32 waves) if ws fits the partial array;
    // else 1024 (R1-equivalent residency). Both divide G4 exactly.
    const int mb = (ws_size >= (size_t)PART_OFF + 2048u * NFEAT * 4u) ? 2048 : 1024;

    compact_k<<<192, 256, 0, stream>>>(msb, lsb, cc, counter);
    feat_main<<<mb, MT, 0, stream>>>(xin, xs, cc, partial, counter, out);
}

// Round 4
// 157.059 us; speedup vs baseline: 2.2769x; 2.2769x over previous
//
#include <hip/hip_runtime.h>

// FeatLUT: out[f] = quantize( mean_p( msb[idx_m(p)][f] + lsb[idx_l(p)][f] ) )
// idx = 16*(289*c0 + 17*c1 + c2)  -> only 17^3 = 4913 distinct rows used.
// Strategy: per-block LDS histogram of the 4913 small indices, per-block dot
// against compacted tables -> NON-ATOMIC per-block partials, tree-reduce.
//
// Session mines (do not re-trip):
//  - 40960 same-cacheline global atomics serialized = 417us (orig R1).
//  - __launch_bounds__ min-waves squeezes VGPR (52->28), serializes load
//    bundles: VALUBusy 6%, 3x slower (R2).
//  - Fused last-block finalize with __threadfence(): agent-scope fence on
//    8-XCD gfx950 = bulk L2 writeback/invalidate per block -> nukes L2 under
//    concurrent streamers; slow even with warm L3 (R2/R3/R4, 3-5x).
// => Keep R1 structure: 3 dispatches, no device fences, distinct-address
//    partial stores. Single change vs R1: PACKED histogram (msb lo16 /
//    lsb hi16, max 4096/field) -> LDS 39.9KB -> 20KB -> 8 blocks/CU
//    (32 waves/CU, 2x latency hiding for the streaming phase).

#define NBINS 4913            // 17^3
#define NPIX  (2048 * 2048)   // 4194304
#define G4    (NPIX / 4)      // 1048576 float4 groups per channel plane
#define NFEAT 20
#define MAIN_BLOCKS 1024      // 8 blocks/CU now (LDS ~20KB)

// ---------------------------------------------------------------------------
// Kernel 0: compact the used LUT rows (row 16*j, j in [0,4913)) into dense
// 20-byte rows stored as 5 dwords each. Handles both harness layouts for the
// int8 tables: (a) raw int8 bytes, (b) widened to int32. Detection: random
// packed bytes essentially never stay in [-32,32) 64x in a row.
// ---------------------------------------------------------------------------
__global__ __launch_bounds__(256) void compact_k(const int* __restrict__ msb,
                                                 const int* __restrict__ lsb,
                                                 int* __restrict__ cm,
                                                 int* __restrict__ cl) {
    int ok = 1;
    for (int i = 0; i < 64; ++i) {
        int v = msb[i];
        ok &= (v >= -32 && v < 32);
    }
    const bool is_int32 = (ok != 0);

    const int total = NBINS * 5;  // dwords per compact table
    int t = blockIdx.x * 256 + threadIdx.x;
    const int stride = gridDim.x * 256;
    for (; t < total; t += stride) {
        int j = t / 5;
        int k = t - j * 5;
        int wm, wl;
        if (is_int32) {
            // source: int per element; row 16j starts at element 16j*20 = 320j
            const int* rm = msb + j * 320 + k * 4;
            const int* rl = lsb + j * 320 + k * 4;
            unsigned um = (unsigned)(rm[0] & 0xff) | ((unsigned)(rm[1] & 0xff) << 8) |
                          ((unsigned)(rm[2] & 0xff) << 16) | ((unsigned)(rm[3] & 0xff) << 24);
            unsigned ul = (unsigned)(rl[0] & 0xff) | ((unsigned)(rl[1] & 0xff) << 8) |
                          ((unsigned)(rl[2] & 0xff) << 16) | ((unsigned)(rl[3] & 0xff) << 24);
            wm = (int)um;
            wl = (int)ul;
        } else {
            // source: raw int8; row 16j at byte 320j -> dword 80j, 5 dwords/row
            wm = msb[j * 80 + k];
            wl = lsb[j * 80 + k];
        }
        cm[t] = wm;
        cl[t] = wl;
    }
}

// ---------------------------------------------------------------------------
// Kernel 1: main. MAIN_BLOCKS x 256 threads.
//  - packed LDS histogram (4913 ints, msb lo16 / lsb hi16; per-block count
//    per table = 4096 < 2^16, no cross-field carry)
//  - float4 streaming of x_in / x_s (exactly 4 grid-stride iters, no tail)
//  - per-block dot against compact tables, wave shuffle reduce, LDS combine,
//    one NON-ATOMIC 20-int partial row per block.
// ---------------------------------------------------------------------------
__global__ __launch_bounds__(256) void feat_main(const float* __restrict__ xin,
                                                 const float* __restrict__ xs,
                                                 const int* __restrict__ cm,
                                                 const int* __restrict__ cl,
                                                 int* __restrict__ partial) {
    __shared__ int hist[NBINS];   // 19652 B -> 8 blocks/CU (was 39.3KB -> 4)
    __shared__ int wsum[4][NFEAT];
    for (int i = threadIdx.x; i < NBINS; i += 256) hist[i] = 0;
    __syncthreads();

    const float4* a = (const float4*)xin;
    const float4* b = (const float4*)xs;
    const int nt = MAIN_BLOCKS * 256;
    for (int g = blockIdx.x * 256 + threadIdx.x; g < G4; g += nt) {
        float4 a0 = a[g], a1 = a[g + G4], a2 = a[g + 2 * G4];
        float4 b0 = b[g], b1 = b[g + G4], b2 = b[g + 2 * G4];

        int m0 = (int)fmaf(a0.x, 289.0f, fmaf(a1.x, 17.0f, a2.x));
        int m1 = (int)fmaf(a0.y, 289.0f, fmaf(a1.y, 17.0f, a2.y));
        int m2 = (int)fmaf(a0.z, 289.0f, fmaf(a1.z, 17.0f, a2.z));
        int m3 = (int)fmaf(a0.w, 289.0f, fmaf(a1.w, 17.0f, a2.w));
        int s0 = (int)fmaf(b0.x, 289.0f, fmaf(b1.x, 17.0f, b2.x));
        int s1 = (int)fmaf(b0.y, 289.0f, fmaf(b1.y, 17.0f, b2.y));
        int s2 = (int)fmaf(b0.z, 289.0f, fmaf(b1.z, 17.0f, b2.z));
        int s3 = (int)fmaf(b0.w, 289.0f, fmaf(b1.w, 17.0f, b2.w));

        atomicAdd(&hist[m0], 1);
        atomicAdd(&hist[m1], 1);
        atomicAdd(&hist[m2], 1);
        atomicAdd(&hist[m3], 1);
        atomicAdd(&hist[s0], 1 << 16);
        atomicAdd(&hist[s1], 1 << 16);
        atomicAdd(&hist[s2], 1 << 16);
        atomicAdd(&hist[s3], 1 << 16);
    }
    __syncthreads();

    // per-block dot product: acc[f] += hm[j]*msb_row[j][f] + hl[j]*lsb_row[j][f]
    int acc[NFEAT];
#pragma unroll
    for (int f = 0; f < NFEAT; ++f) acc[f] = 0;

    for (int j = threadIdx.x; j < NBINS; j += 256) {
        int h = hist[j];
        int hm = h & 0xffff;
        int hl = (int)((unsigned)h >> 16);
        if (hm) {
            const int* r = cm + j * 5;
#pragma unroll
            for (int k = 0; k < 5; ++k) {
                int w = r[k];
                acc[4 * k + 0] += hm * ((w << 24) >> 24);
                acc[4 * k + 1] += hm * ((w << 16) >> 24);
                acc[4 * k + 2] += hm * ((w << 8) >> 24);
                acc[4 * k + 3] += hm * (w >> 24);
            }
        }
        if (hl) {
            const int* r = cl + j * 5;
#pragma unroll
            for (int k = 0; k < 5; ++k) {
                int w = r[k];
                acc[4 * k + 0] += hl * ((w << 24) >> 24);
                acc[4 * k + 1] += hl * ((w << 16) >> 24);
                acc[4 * k + 2] += hl * ((w << 8) >> 24);
                acc[4 * k + 3] += hl * (w >> 24);
            }
        }
    }

    // wave butterfly reduce -> LDS per-wave row -> thread f sums 4 rows ->
    // one non-atomic global partial row per block.
    const int lane = threadIdx.x & 63;
    const int wv = threadIdx.x >> 6;
#pragma unroll
    for (int f = 0; f < NFEAT; ++f) {
        int v = acc[f];
#pragma unroll
        for (int o = 32; o > 0; o >>= 1) v += __shfl_xor(v, o, 64);
        if (lane == 0) wsum[wv][f] = v;
    }
    __syncthreads();
    if (threadIdx.x < NFEAT) {
        int f = threadIdx.x;
        partial[blockIdx.x * NFEAT + f] = wsum[0][f] + wsum[1][f] + wsum[2][f] + wsum[3][f];
    }
}

// ---------------------------------------------------------------------------
// Kernel 2: finalize. Block f (of 20) sums partial[b][f] over 1024 blocks,
// then quantizes exactly: mean*4 = S / 2^20; RNE rint == jnp.round.
// ---------------------------------------------------------------------------
__global__ __launch_bounds__(64) void finalize_k(const int* __restrict__ partial,
                                                 float* __restrict__ out) {
    const int f = blockIdx.x;
    const int lane = threadIdx.x;
    int s = 0;
    for (int b = lane; b < MAIN_BLOCKS; b += 64) s += partial[b * NFEAT + f];
#pragma unroll
    for (int o = 32; o > 0; o >>= 1) s += __shfl_xor(s, o, 64);
    if (lane == 0) {
        double m4 = (double)s * (1.0 / 1048576.0);
        double r = rint(m4);
        float v = (float)(r * 0.25);
        v = fminf(fmaxf(v, -32.0f), 31.75f);
        out[f] = v;
    }
}

extern "C" void kernel_launch(void* const* d_in, const int* in_sizes, int n_in,
                              void* d_out, int out_size, void* d_ws, size_t ws_size,
                              hipStream_t stream) {
    const float* xin = (const float*)d_in[0];
    const float* xs = (const float*)d_in[1];
    const int* msb = (const int*)d_in[2];
    const int* lsb = (const int*)d_in[3];
    float* out = (float*)d_out;

    // workspace layout: compact tables (2 x 96 KiB), then per-block partials
    int* cm = (int*)d_ws;
    int* cl = (int*)((char*)d_ws + 98304);
    int* partial = (int*)((char*)d_ws + 2 * 98304);  // 1024*20*4 = 80 KiB

    compact_k<<<96, 256, 0, stream>>>(msb, lsb, cm, cl);
    feat_main<<<MAIN_BLOCKS, 256, 0, stream>>>(xin, xs, cm, cl, partial);
    finalize_k<<<NFEAT, 64, 0, stream>>>(partial, out);
}